// Round 1
// baseline (685.801 us; speedup 1.0000x reference)
//
#include <hip/hip_runtime.h>
#include <hip/hip_bf16.h>
#include <cstdint>
#include <cstddef>

using bf16 = __hip_bfloat16;

typedef __bf16 bf16x8_t __attribute__((ext_vector_type(8)));
typedef float  f32x4_t  __attribute__((ext_vector_type(4)));

static constexpr int Bb = 2;
static constexpr int Tt = 4096;
static constexpr int Gg = 4;
static constexpr int Cc = 1024;
static constexpr int Mm = Bb * Tt;   // 8192 rows (b*T+t)
static constexpr int GC = Gg * Cc;   // 4096

__device__ __forceinline__ float bfbits2f(unsigned u) {
  union { unsigned i; float f; } c; c.i = u << 16; return c.f;
}
__device__ __forceinline__ ushort f2bfbits(float v) {
  union { __hip_bfloat16 h; ushort u; } c; c.h = __float2bfloat16(v); return c.u;
}

__device__ __forceinline__ void store_val(bf16* p, float v)  { *p = __float2bfloat16(v); }
__device__ __forceinline__ void store_val(float* p, float v) { *p = v; }

// global -> LDS direct DMA, 16 B per lane. LDS dest must be the wave-uniform
// base (HW computes base + lane*16); global address is per-lane.
__device__ __forceinline__ void gld_lds16(const ushort* g, ushort* l) {
  __builtin_amdgcn_global_load_lds(
      (const __attribute__((address_space(1))) void*)g,
      (__attribute__((address_space(3))) void*)l, 16, 0, 0);
}

// ---------------------------------------------------------------------------
// fp32 -> bf16 (plain) and fp32 -> (hi, lo) split: hi = bf16(x),
// lo = bf16(x - hi). x-hi is exact in fp32 (Sterbenz), so hi+lo carries
// ~16 mantissa bits; bf16's fp32 exponent range means no subnormal hazards.
// ---------------------------------------------------------------------------
__global__ __launch_bounds__(256)
void cvt_bf16(const float* __restrict__ in, ushort* __restrict__ out, int n4)
{
  const int i = blockIdx.x * 256 + threadIdx.x;
  if (i >= n4) return;
  const float4 v = ((const float4*)in)[i];
  ushort4 o;
  o.x = f2bfbits(v.x); o.y = f2bfbits(v.y);
  o.z = f2bfbits(v.z); o.w = f2bfbits(v.w);
  ((ushort4*)out)[i] = o;
}

__global__ __launch_bounds__(256)
void cvt_split(const float* __restrict__ in, ushort* __restrict__ hi,
               ushort* __restrict__ lo, int n4)
{
  const int i = blockIdx.x * 256 + threadIdx.x;
  if (i >= n4) return;
  const float4 v = ((const float4*)in)[i];
  ushort4 h, l;
  h.x = f2bfbits(v.x); l.x = f2bfbits(v.x - bfbits2f(h.x));
  h.y = f2bfbits(v.y); l.y = f2bfbits(v.y - bfbits2f(h.y));
  h.z = f2bfbits(v.z); l.z = f2bfbits(v.z - bfbits2f(h.z));
  h.w = f2bfbits(v.w); l.w = f2bfbits(v.w - bfbits2f(h.w));
  ((ushort4*)hi)[i] = h;
  ((ushort4*)lo)[i] = l;
}

// ---------------------------------------------------------------------------
// GEMM1 (fused): 3-pass split-bf16  k = embH@kwH^T + embH@kwL^T + embL@kwH^T
// + key_b, accumulated in fp32 AGPRs across all passes. kall is NOT stored;
// the epilogue computes per-(row,g) partials sum k^2, sum k*wk*q*wq, sum q^2
// over this block's 128 cols and atomicAdds them (fp32, device scope).
// 128x128 tile, BK=64, 4 waves 2x2.
// R1 change: staging is now global_load_lds width=16 into LINEAR [128][64]
// LDS (m97 structure, 874 TF measured vs 646 reg-staged at this tile).
// A-frag A[m=lane&15][k=(lane>>4)*8+j]; C/D col=lane&15,row=(lane>>4)*4+reg
// (both validated end-to-end by the earlier 0.094-absmax run; numerics
// unchanged by the staging rewrite).
// ---------------------------------------------------------------------------
__global__ __launch_bounds__(256, 2)
void gemm_key_fused(const ushort* __restrict__ embH, const ushort* __restrict__ embL,
                    const ushort* __restrict__ kwH,  const ushort* __restrict__ kwL,
                    const float* __restrict__ key_b, const float* __restrict__ hid,
                    const float* __restrict__ wkn,   const float* __restrict__ wqn,
                    float* __restrict__ k2_part, float* __restrict__ dot_part,
                    float* __restrict__ q2_part)
{
  constexpr int K = Cc;  // 1024
  __shared__ __align__(16) ushort sA[128 * 64];
  __shared__ __align__(16) ushort sB[128 * 64];

  const int tid  = threadIdx.x;
  const int lane = tid & 63;
  const int wave = tid >> 6;
  const int wm   = wave & 1;
  const int wn   = wave >> 1;
  const int row0 = blockIdx.y * 128;
  const int col0 = blockIdx.x * 128;

  // staging geometry: round p covers rows [p*32, p*32+32); thread t covers
  // row p*32 + (t>>3), col elems (t&7)*8. LDS dest is linear: lane*16 bytes
  // off the wave base (p*2048 + wave*512 elems).
  const int srow = tid >> 3;          // 0..31 within a round
  const int scol = (tid & 7) * 8;     // 0..56
  ushort* aWB = sA + wave * 512;      // + p*2048 per round
  ushort* bWB = sB + wave * 512;

  f32x4_t acc[4][4] = {};

  const ushort* Asrc[3] = { embH, embH, embL };
  const ushort* Bsrc[3] = { kwH,  kwL,  kwH  };

  for (int pass = 0; pass < 3; ++pass) {
    const ushort* __restrict__ A  = Asrc[pass];
    const ushort* __restrict__ Bm = Bsrc[pass];
    for (int kt = 0; kt < K; kt += 64) {
#pragma unroll
      for (int p = 0; p < 4; ++p) {
        gld_lds16(A  + (size_t)(row0 + p * 32 + srow) * K + kt + scol,
                  aWB + p * 2048);
        gld_lds16(Bm + (size_t)(col0 + p * 32 + srow) * K + kt + scol,
                  bWB + p * 2048);
      }
      __syncthreads();   // compiler emits vmcnt(0) drain before the barrier

#pragma unroll
      for (int ks = 0; ks < 2; ++ks) {
        const int cb = ks * 4 + (lane >> 4);
        bf16x8_t af[4], bfr[4];
#pragma unroll
        for (int mi = 0; mi < 4; ++mi) {
          const int r = wm * 64 + mi * 16 + (lane & 15);
          af[mi] = *(const bf16x8_t*)(sA + r * 64 + cb * 8);
        }
#pragma unroll
        for (int ni = 0; ni < 4; ++ni) {
          const int r = wn * 64 + ni * 16 + (lane & 15);
          bfr[ni] = *(const bf16x8_t*)(sB + r * 64 + cb * 8);
        }
#pragma unroll
        for (int mi = 0; mi < 4; ++mi)
#pragma unroll
          for (int ni = 0; ni < 4; ++ni)
            acc[mi][ni] = __builtin_amdgcn_mfma_f32_16x16x32_bf16(
                af[mi], bfr[ni], acc[mi][ni], 0, 0, 0);
      }
      __syncthreads();
    }
  }

  // ---- fused gate-reduction epilogue ----
  const int lrow = lane >> 4;
  const int lcol = lane & 15;
  const int g    = col0 >> 10;   // 128-col block lies within one group

  float s2[4][4] = {};  // [mi][reg] sum_ni k^2
  float su[4][4] = {};  // [mi][reg] sum_ni k*wk*q*wq
  float sq[4][4] = {};  // [mi][reg] sum_ni q^2

#pragma unroll
  for (int ni = 0; ni < 4; ++ni) {
    const int col = col0 + wn * 64 + ni * 16 + lcol;
    const float kb = key_b[col];
    const float ww = wkn[col] * wqn[col];
#pragma unroll
    for (int mi = 0; mi < 4; ++mi) {
      const int rowb = row0 + wm * 64 + mi * 16 + lrow * 4;
#pragma unroll
      for (int r = 0; r < 4; ++r) {
        const float q = hid[(size_t)(rowb + r) * GC + col];
        const float k = acc[mi][ni][r] + kb;
        s2[mi][r] += k * k;
        su[mi][r] += k * ww * q;
        sq[mi][r] += q * q;
      }
    }
  }
  // reduce across the 16 lanes (lane&15) holding the same rows
#pragma unroll
  for (int off = 1; off < 16; off <<= 1) {
#pragma unroll
    for (int mi = 0; mi < 4; ++mi)
#pragma unroll
      for (int r = 0; r < 4; ++r) {
        s2[mi][r] += __shfl_xor(s2[mi][r], off);
        su[mi][r] += __shfl_xor(su[mi][r], off);
        sq[mi][r] += __shfl_xor(sq[mi][r], off);
      }
  }
  if (lcol == 0) {
#pragma unroll
    for (int mi = 0; mi < 4; ++mi) {
      const int rowb = row0 + wm * 64 + mi * 16 + lrow * 4;
#pragma unroll
      for (int r = 0; r < 4; ++r) {
        atomicAdd(&k2_part[(rowb + r) * Gg + g],  s2[mi][r]);
        atomicAdd(&dot_part[(rowb + r) * Gg + g], su[mi][r]);
        atomicAdd(&q2_part[(rowb + r) * Gg + g],  sq[mi][r]);
      }
    }
  }
}

// ---------------------------------------------------------------------------
// GEMM2: vproj = embH @ vwB^T + val_b  (plain bf16, fp32 out).
// Same global_load_lds staging rewrite as GEMM1.
// ---------------------------------------------------------------------------
template <typename OutT>
__global__ __launch_bounds__(256, 2)
void gemm_bt(const ushort* __restrict__ A, const ushort* __restrict__ Bm,
             const float* __restrict__ bias, OutT* __restrict__ C,
             int M, int N, int K)
{
  __shared__ __align__(16) ushort sA[128 * 64];
  __shared__ __align__(16) ushort sB[128 * 64];

  const int tid  = threadIdx.x;
  const int lane = tid & 63;
  const int wave = tid >> 6;
  const int wm   = wave & 1;
  const int wn   = wave >> 1;
  const int row0 = blockIdx.y * 128;
  const int col0 = blockIdx.x * 128;

  const int srow = tid >> 3;
  const int scol = (tid & 7) * 8;
  ushort* aWB = sA + wave * 512;
  ushort* bWB = sB + wave * 512;

  f32x4_t acc[4][4] = {};

  for (int kt = 0; kt < K; kt += 64) {
#pragma unroll
    for (int p = 0; p < 4; ++p) {
      gld_lds16(A  + (size_t)(row0 + p * 32 + srow) * K + kt + scol,
                aWB + p * 2048);
      gld_lds16(Bm + (size_t)(col0 + p * 32 + srow) * K + kt + scol,
                bWB + p * 2048);
    }
    __syncthreads();

#pragma unroll
    for (int ks = 0; ks < 2; ++ks) {
      const int cb = ks * 4 + (lane >> 4);
      bf16x8_t af[4], bfr[4];
#pragma unroll
      for (int mi = 0; mi < 4; ++mi) {
        const int r = wm * 64 + mi * 16 + (lane & 15);
        af[mi] = *(const bf16x8_t*)(sA + r * 64 + cb * 8);
      }
#pragma unroll
      for (int ni = 0; ni < 4; ++ni) {
        const int r = wn * 64 + ni * 16 + (lane & 15);
        bfr[ni] = *(const bf16x8_t*)(sB + r * 64 + cb * 8);
      }
#pragma unroll
      for (int mi = 0; mi < 4; ++mi)
#pragma unroll
        for (int ni = 0; ni < 4; ++ni)
          acc[mi][ni] = __builtin_amdgcn_mfma_f32_16x16x32_bf16(
              af[mi], bfr[ni], acc[mi][ni], 0, 0, 0);
    }
    __syncthreads();
  }

  const int lrow = lane >> 4;
  const int lcol = lane & 15;
#pragma unroll
  for (int ni = 0; ni < 4; ++ni) {
    const int col = col0 + wn * 64 + ni * 16 + lcol;
    const float bv = bias[col];
#pragma unroll
    for (int mi = 0; mi < 4; ++mi) {
      const int rowb = row0 + wm * 64 + mi * 16 + lrow * 4;
#pragma unroll
      for (int r = 0; r < 4; ++r)
        store_val(&C[(size_t)(rowb + r) * N + col], acc[mi][ni][r] + bv);
    }
  }
}

// ---------------------------------------------------------------------------
// Finalize: per (b,t) compute mean(vproj^2); combine with atomic partials to
// produce gate[b,t,g] and snorm[b,t,g] = gate/rms_v.
// ---------------------------------------------------------------------------
__global__ __launch_bounds__(256)
void finalize_kernel(const float* __restrict__ vproj,
                     const float* __restrict__ k2_part,
                     const float* __restrict__ dot_part,
                     const float* __restrict__ q2_part,
                     float* __restrict__ gate_o, float* __restrict__ snorm_o)
{
  const int bt   = blockIdx.x;
  const int tid  = threadIdx.x;
  const int g    = tid >> 6;
  const int lane = tid & 63;

  const float4 v4 = ((const float4*)(vproj + (size_t)bt * Cc))[tid];
  float pv = v4.x * v4.x + v4.y * v4.y + v4.z * v4.z + v4.w * v4.w;
#pragma unroll
  for (int off = 32; off > 0; off >>= 1) pv += __shfl_xor(pv, off);
  __shared__ float wsum[4];
  if (lane == 0) wsum[g] = pv;
  __syncthreads();

  if (lane == 0) {
    const float mv = (wsum[0] + wsum[1] + wsum[2] + wsum[3]) * (1.0f / 1024.0f);
    const float sk = k2_part[bt * Gg + g];
    const float sd = dot_part[bt * Gg + g];
    const float sq = q2_part[bt * Gg + g];
    const float rk = sqrtf(sk * (1.0f / 1024.0f) + 1e-5f);
    const float rq = sqrtf(sq * (1.0f / 1024.0f) + 1e-5f);
    const float graw = sd / (rk * rq) * (1.0f / 32.0f);   // sqrt(C)=32
    const float sgn = (graw >= 0.f) ? 1.f : -1.f;
    const float gate = 1.f / (1.f + expf(-sgn * sqrtf(fmaxf(fabsf(graw), 1e-6f))));
    const float rv = sqrtf(gate * gate * mv + 1e-5f);
    gate_o[bt * Gg + g]  = gate;
    snorm_o[bt * Gg + g] = gate / rv;
  }
}

// ---------------------------------------------------------------------------
// Conv: lags {0,3,6,9} share t mod 3 -> 3 phase subsequences, lag-1 K=4 conv.
// Thread = (b,g,c,phase,chunk); 3 running normed values; 3-step halo.
// ---------------------------------------------------------------------------
static constexpr int CJ  = 128;
static constexpr int NCH = 11;   // ceil(ceil(4096/3)/128)

__global__ __launch_bounds__(256)
void conv_kernel(const float* __restrict__ vproj, const float* __restrict__ gate,
                 const float* __restrict__ snorm, const float* __restrict__ wnm,
                 const float* __restrict__ cw, float* __restrict__ out)
{
  int x = blockIdx.x;
  const int cb = x & 3;  x >>= 2;
  const int p  = x % 3;  x /= 3;
  const int ch = x % NCH; x /= NCH;
  const int g  = x & 3;  x >>= 2;
  const int b  = x;
  const int c  = cb * 256 + threadIdx.x;

  const float wn = wnm[g * Cc + c];
  const float4 w = ((const float4*)cw)[g * Cc + c];

  int t = p + 3 * (ch * CJ);
  if (t >= Tt) return;

  float n1 = 0.f, n2 = 0.f, n3 = 0.f;
#pragma unroll
  for (int h = 3; h >= 1; --h) {
    const int th = t - 3 * h;
    float nv = 0.f;
    if (th >= 0) {
      const int bt = b * Tt + th;
      nv = vproj[(size_t)bt * Cc + c] * snorm[bt * Gg + g] * wn;
    }
    n3 = n2; n2 = n1; n1 = nv;
  }

  for (int j = 0; j < CJ && t < Tt; ++j, t += 3) {
    const int bt = b * Tt + t;
    const float vp  = vproj[(size_t)bt * Cc + c];
    const float gt  = gate[bt * Gg + g];
    const float sn  = snorm[bt * Gg + g];
    const float cur = vp * sn * wn;
    const float a   = w.x * n3 + w.y * n2 + w.z * n1 + w.w * cur;
    const float si  = a / (1.f + __expf(-a));
    out[((size_t)bt * Gg + g) * Cc + c] = vp * gt + si;
    n3 = n2; n2 = n1; n1 = cur;
  }
}

// ---------------------------------------------------------------------------
extern "C" void kernel_launch(void* const* d_in, const int* in_sizes, int n_in,
                              void* d_out, int out_size, void* d_ws, size_t ws_size,
                              hipStream_t stream)
{
  const float* emb   = (const float*)d_in[0];
  const float* hid   = (const float*)d_in[1];
  const float* key_w = (const float*)d_in[2];
  const float* key_b = (const float*)d_in[3];
  const float* val_w = (const float*)d_in[4];
  const float* val_b = (const float*)d_in[5];
  const float* wkn   = (const float*)d_in[6];
  const float* wqn   = (const float*)d_in[7];
  const float* wnm   = (const float*)d_in[8];
  const float* cwt   = (const float*)d_in[9];
  float* out = (float*)d_out;

  // ws: embH 16.8M | embL 16.8M | kwH 8.4M | kwL 8.4M | vwB 2.1M |
  //     vproj 33.5M | k2/dot/q2/gate/snorm 5x128K   (~86.6 MB)
  char* ws = (char*)d_ws;
  ushort* embH  = (ushort*)ws;  ws += (size_t)Mm * Cc * 2;
  ushort* embL  = (ushort*)ws;  ws += (size_t)Mm * Cc * 2;
  ushort* kwH   = (ushort*)ws;  ws += (size_t)GC * Cc * 2;
  ushort* kwL   = (ushort*)ws;  ws += (size_t)GC * Cc * 2;
  ushort* vwB   = (ushort*)ws;  ws += (size_t)Cc * Cc * 2;
  float*  vproj = (float*)ws;   ws += (size_t)Mm * Cc * 4;
  float*  k2p   = (float*)ws;   ws += (size_t)Mm * Gg * 4;
  float*  dotp  = (float*)ws;   ws += (size_t)Mm * Gg * 4;
  float*  q2p   = (float*)ws;   ws += (size_t)Mm * Gg * 4;
  float*  gate  = (float*)ws;   ws += (size_t)Mm * Gg * 4;
  float*  snorm = (float*)ws;

  // zero the atomic partials (contiguous k2p|dotp|q2p)
  hipMemsetAsync(k2p, 0, (size_t)3 * Mm * Gg * 4, stream);

  dim3 blk(256);
  cvt_split<<<dim3((Mm * Cc / 4) / 256), blk, 0, stream>>>(emb,   embH, embL, Mm * Cc / 4);
  cvt_split<<<dim3((GC * Cc / 4) / 256), blk, 0, stream>>>(key_w, kwH,  kwL,  GC * Cc / 4);
  cvt_bf16 <<<dim3((Cc * Cc / 4) / 256), blk, 0, stream>>>(val_w, vwB,  Cc * Cc / 4);

  gemm_key_fused<<<dim3(GC / 128, Mm / 128), blk, 0, stream>>>(
      embH, embL, kwH, kwL, key_b, hid, wkn, wqn, k2p, dotp, q2p);

  gemm_bt<float><<<dim3(Cc / 128, Mm / 128), blk, 0, stream>>>(
      embH, vwB, val_b, vproj, Mm, Cc, Cc);

  finalize_kernel<<<dim3(Mm), blk, 0, stream>>>(vproj, k2p, dotp, q2p, gate, snorm);

  const int nblocks = Bb * Gg * NCH * 3 * (Cc / 256);  // 1056
  conv_kernel<<<dim3(nblocks), blk, 0, stream>>>(vproj, gate, snorm, wnm, cwt, out);
}

// Round 2
// 637.156 us; speedup vs baseline: 1.0763x; 1.0763x over previous
//
#include <hip/hip_runtime.h>
#include <hip/hip_bf16.h>
#include <cstdint>
#include <cstddef>

using bf16 = __hip_bfloat16;

typedef __bf16 bf16x8_t __attribute__((ext_vector_type(8)));
typedef float  f32x4_t  __attribute__((ext_vector_type(4)));

static constexpr int Bb = 2;
static constexpr int Tt = 4096;
static constexpr int Gg = 4;
static constexpr int Cc = 1024;
static constexpr int Mm = Bb * Tt;   // 8192 rows (b*T+t)
static constexpr int GC = Gg * Cc;   // 4096

__device__ __forceinline__ float bfbits2f(unsigned u) {
  union { unsigned i; float f; } c; c.i = u << 16; return c.f;
}
__device__ __forceinline__ ushort f2bfbits(float v) {
  union { __hip_bfloat16 h; ushort u; } c; c.h = __float2bfloat16(v); return c.u;
}

__device__ __forceinline__ void store_val(bf16* p, float v)  { *p = __float2bfloat16(v); }
__device__ __forceinline__ void store_val(float* p, float v) { *p = v; }

// global -> LDS direct DMA, 16 B per lane. LDS dest must be the wave-uniform
// base (HW computes base + lane*16); global address is per-lane.
__device__ __forceinline__ void gld_lds16(const ushort* g, ushort* l) {
  __builtin_amdgcn_global_load_lds(
      (const __attribute__((address_space(1))) void*)g,
      (__attribute__((address_space(3))) void*)l, 16, 0, 0);
}

// ---------------------------------------------------------------------------
// fp32 -> bf16 (plain) and fp32 -> (hi, lo) split: hi = bf16(x),
// lo = bf16(x - hi). x-hi is exact in fp32 (Sterbenz), so hi+lo carries
// ~16 mantissa bits; bf16's fp32 exponent range means no subnormal hazards.
// ---------------------------------------------------------------------------
__global__ __launch_bounds__(256)
void cvt_bf16(const float* __restrict__ in, ushort* __restrict__ out, int n4)
{
  const int i = blockIdx.x * 256 + threadIdx.x;
  if (i >= n4) return;
  const float4 v = ((const float4*)in)[i];
  ushort4 o;
  o.x = f2bfbits(v.x); o.y = f2bfbits(v.y);
  o.z = f2bfbits(v.z); o.w = f2bfbits(v.w);
  ((ushort4*)out)[i] = o;
}

__global__ __launch_bounds__(256)
void cvt_split(const float* __restrict__ in, ushort* __restrict__ hi,
               ushort* __restrict__ lo, int n4)
{
  const int i = blockIdx.x * 256 + threadIdx.x;
  if (i >= n4) return;
  const float4 v = ((const float4*)in)[i];
  ushort4 h, l;
  h.x = f2bfbits(v.x); l.x = f2bfbits(v.x - bfbits2f(h.x));
  h.y = f2bfbits(v.y); l.y = f2bfbits(v.y - bfbits2f(h.y));
  h.z = f2bfbits(v.z); l.z = f2bfbits(v.z - bfbits2f(h.z));
  h.w = f2bfbits(v.w); l.w = f2bfbits(v.w - bfbits2f(h.w));
  ((ushort4*)hi)[i] = h;
  ((ushort4*)lo)[i] = l;
}

// ---------------------------------------------------------------------------
// GEMM1 (fused): 3-pass split-bf16  k = embH@kwH^T + embH@kwL^T + embL@kwH^T
// + key_b, accumulated in fp32 AGPRs across all passes. kall is NOT stored;
// the epilogue computes per-(row,g) partials sum k^2, sum k*wk*q*wq, sum q^2
// over this block's 128 cols and atomicAdds them (fp32, device scope).
// 128x128 tile, BK=64, 4 waves 2x2, global_load_lds width=16, linear LDS.
// R2 change: T2 XOR-swizzle (rule #21: linear LDS dest + inverse-swizzled
// GLOBAL source + same swizzle on ds_read). LDS elem (r, ce) holds global
// (r, ce ^ ((r&7)<<3)); involution, bit-identical numerics. Kills the
// 16-way read bank conflict of the linear [128][64] layout (R1 counters:
// SQ_LDS_BANK_CONFLICT 7.55e7 ~= 31% of all cycles).
// A-frag A[m=lane&15][k=(lane>>4)*8+j]; C/D col=lane&15,row=(lane>>4)*4+reg.
// ---------------------------------------------------------------------------
__global__ __launch_bounds__(256, 2)
void gemm_key_fused(const ushort* __restrict__ embH, const ushort* __restrict__ embL,
                    const ushort* __restrict__ kwH,  const ushort* __restrict__ kwL,
                    const float* __restrict__ key_b, const float* __restrict__ hid,
                    const float* __restrict__ wkn,   const float* __restrict__ wqn,
                    float* __restrict__ k2_part, float* __restrict__ dot_part,
                    float* __restrict__ q2_part)
{
  constexpr int K = Cc;  // 1024
  __shared__ __align__(16) ushort sA[128 * 64];
  __shared__ __align__(16) ushort sB[128 * 64];

  const int tid  = threadIdx.x;
  const int lane = tid & 63;
  const int wave = tid >> 6;
  const int wm   = wave & 1;
  const int wn   = wave >> 1;
  const int row0 = blockIdx.y * 128;
  const int col0 = blockIdx.x * 128;

  // staging geometry: round p covers rows [p*32, p*32+32); thread t covers
  // row p*32 + (t>>3). LDS dest is linear (lane*16 B off the wave base);
  // the SOURCE column is pre-swizzled so that LDS holds the st-8x64 layout.
  const int srow = tid >> 3;                                  // 0..31
  const int scol = ((tid & 7) ^ (srow & 7)) * 8;              // swizzled col
  ushort* aWB = sA + wave * 512;                              // + p*2048/round
  ushort* bWB = sB + wave * 512;

  f32x4_t acc[4][4] = {};

  const ushort* Asrc[3] = { embH, embH, embL };
  const ushort* Bsrc[3] = { kwH,  kwL,  kwH  };

  for (int pass = 0; pass < 3; ++pass) {
    const ushort* __restrict__ A  = Asrc[pass];
    const ushort* __restrict__ Bm = Bsrc[pass];
    for (int kt = 0; kt < K; kt += 64) {
#pragma unroll
      for (int p = 0; p < 4; ++p) {
        gld_lds16(A  + (size_t)(row0 + p * 32 + srow) * K + kt + scol,
                  aWB + p * 2048);
        gld_lds16(Bm + (size_t)(col0 + p * 32 + srow) * K + kt + scol,
                  bWB + p * 2048);
      }
      __syncthreads();

#pragma unroll
      for (int ks = 0; ks < 2; ++ks) {
        const int cb  = ks * 4 + (lane >> 4);
        const int ce  = ((cb ^ (lane & 7)) * 8);   // swizzled read col (elems)
        bf16x8_t af[4], bfr[4];
#pragma unroll
        for (int mi = 0; mi < 4; ++mi) {
          const int r = wm * 64 + mi * 16 + (lane & 15);
          af[mi] = *(const bf16x8_t*)(sA + r * 64 + ce);
        }
#pragma unroll
        for (int ni = 0; ni < 4; ++ni) {
          const int r = wn * 64 + ni * 16 + (lane & 15);
          bfr[ni] = *(const bf16x8_t*)(sB + r * 64 + ce);
        }
#pragma unroll
        for (int mi = 0; mi < 4; ++mi)
#pragma unroll
          for (int ni = 0; ni < 4; ++ni)
            acc[mi][ni] = __builtin_amdgcn_mfma_f32_16x16x32_bf16(
                af[mi], bfr[ni], acc[mi][ni], 0, 0, 0);
      }
      __syncthreads();
    }
  }

  // ---- fused gate-reduction epilogue ----
  const int lrow = lane >> 4;
  const int lcol = lane & 15;
  const int g    = col0 >> 10;   // 128-col block lies within one group

  float s2[4][4] = {};  // [mi][reg] sum_ni k^2
  float su[4][4] = {};  // [mi][reg] sum_ni k*wk*q*wq
  float sq[4][4] = {};  // [mi][reg] sum_ni q^2

#pragma unroll
  for (int ni = 0; ni < 4; ++ni) {
    const int col = col0 + wn * 64 + ni * 16 + lcol;
    const float kb = key_b[col];
    const float ww = wkn[col] * wqn[col];
#pragma unroll
    for (int mi = 0; mi < 4; ++mi) {
      const int rowb = row0 + wm * 64 + mi * 16 + lrow * 4;
#pragma unroll
      for (int r = 0; r < 4; ++r) {
        const float q = hid[(size_t)(rowb + r) * GC + col];
        const float k = acc[mi][ni][r] + kb;
        s2[mi][r] += k * k;
        su[mi][r] += k * ww * q;
        sq[mi][r] += q * q;
      }
    }
  }
  // reduce across the 16 lanes (lane&15) holding the same rows
#pragma unroll
  for (int off = 1; off < 16; off <<= 1) {
#pragma unroll
    for (int mi = 0; mi < 4; ++mi)
#pragma unroll
      for (int r = 0; r < 4; ++r) {
        s2[mi][r] += __shfl_xor(s2[mi][r], off);
        su[mi][r] += __shfl_xor(su[mi][r], off);
        sq[mi][r] += __shfl_xor(sq[mi][r], off);
      }
  }
  if (lcol == 0) {
#pragma unroll
    for (int mi = 0; mi < 4; ++mi) {
      const int rowb = row0 + wm * 64 + mi * 16 + lrow * 4;
#pragma unroll
      for (int r = 0; r < 4; ++r) {
        atomicAdd(&k2_part[(rowb + r) * Gg + g],  s2[mi][r]);
        atomicAdd(&dot_part[(rowb + r) * Gg + g], su[mi][r]);
        atomicAdd(&q2_part[(rowb + r) * Gg + g],  sq[mi][r]);
      }
    }
  }
}

// ---------------------------------------------------------------------------
// GEMM2: vproj = embH @ vwB^T + val_b  (plain bf16, fp32 out).
// Same T2 swizzle as GEMM1.
// ---------------------------------------------------------------------------
template <typename OutT>
__global__ __launch_bounds__(256, 2)
void gemm_bt(const ushort* __restrict__ A, const ushort* __restrict__ Bm,
             const float* __restrict__ bias, OutT* __restrict__ C,
             int M, int N, int K)
{
  __shared__ __align__(16) ushort sA[128 * 64];
  __shared__ __align__(16) ushort sB[128 * 64];

  const int tid  = threadIdx.x;
  const int lane = tid & 63;
  const int wave = tid >> 6;
  const int wm   = wave & 1;
  const int wn   = wave >> 1;
  const int row0 = blockIdx.y * 128;
  const int col0 = blockIdx.x * 128;

  const int srow = tid >> 3;
  const int scol = ((tid & 7) ^ (srow & 7)) * 8;
  ushort* aWB = sA + wave * 512;
  ushort* bWB = sB + wave * 512;

  f32x4_t acc[4][4] = {};

  for (int kt = 0; kt < K; kt += 64) {
#pragma unroll
    for (int p = 0; p < 4; ++p) {
      gld_lds16(A  + (size_t)(row0 + p * 32 + srow) * K + kt + scol,
                aWB + p * 2048);
      gld_lds16(Bm + (size_t)(col0 + p * 32 + srow) * K + kt + scol,
                bWB + p * 2048);
    }
    __syncthreads();

#pragma unroll
    for (int ks = 0; ks < 2; ++ks) {
      const int cb = ks * 4 + (lane >> 4);
      const int ce = ((cb ^ (lane & 7)) * 8);
      bf16x8_t af[4], bfr[4];
#pragma unroll
      for (int mi = 0; mi < 4; ++mi) {
        const int r = wm * 64 + mi * 16 + (lane & 15);
        af[mi] = *(const bf16x8_t*)(sA + r * 64 + ce);
      }
#pragma unroll
      for (int ni = 0; ni < 4; ++ni) {
        const int r = wn * 64 + ni * 16 + (lane & 15);
        bfr[ni] = *(const bf16x8_t*)(sB + r * 64 + ce);
      }
#pragma unroll
      for (int mi = 0; mi < 4; ++mi)
#pragma unroll
        for (int ni = 0; ni < 4; ++ni)
          acc[mi][ni] = __builtin_amdgcn_mfma_f32_16x16x32_bf16(
              af[mi], bfr[ni], acc[mi][ni], 0, 0, 0);
    }
    __syncthreads();
  }

  const int lrow = lane >> 4;
  const int lcol = lane & 15;
#pragma unroll
  for (int ni = 0; ni < 4; ++ni) {
    const int col = col0 + wn * 64 + ni * 16 + lcol;
    const float bv = bias[col];
#pragma unroll
    for (int mi = 0; mi < 4; ++mi) {
      const int rowb = row0 + wm * 64 + mi * 16 + lrow * 4;
#pragma unroll
      for (int r = 0; r < 4; ++r)
        store_val(&C[(size_t)(rowb + r) * N + col], acc[mi][ni][r] + bv);
    }
  }
}

// ---------------------------------------------------------------------------
// Finalize: per (b,t) compute mean(vproj^2); combine with atomic partials to
// produce gate[b,t,g] and snorm[b,t,g] = gate/rms_v.
// ---------------------------------------------------------------------------
__global__ __launch_bounds__(256)
void finalize_kernel(const float* __restrict__ vproj,
                     const float* __restrict__ k2_part,
                     const float* __restrict__ dot_part,
                     const float* __restrict__ q2_part,
                     float* __restrict__ gate_o, float* __restrict__ snorm_o)
{
  const int bt   = blockIdx.x;
  const int tid  = threadIdx.x;
  const int g    = tid >> 6;
  const int lane = tid & 63;

  const float4 v4 = ((const float4*)(vproj + (size_t)bt * Cc))[tid];
  float pv = v4.x * v4.x + v4.y * v4.y + v4.z * v4.z + v4.w * v4.w;
#pragma unroll
  for (int off = 32; off > 0; off >>= 1) pv += __shfl_xor(pv, off);
  __shared__ float wsum[4];
  if (lane == 0) wsum[g] = pv;
  __syncthreads();

  if (lane == 0) {
    const float mv = (wsum[0] + wsum[1] + wsum[2] + wsum[3]) * (1.0f / 1024.0f);
    const float sk = k2_part[bt * Gg + g];
    const float sd = dot_part[bt * Gg + g];
    const float sq = q2_part[bt * Gg + g];
    const float rk = sqrtf(sk * (1.0f / 1024.0f) + 1e-5f);
    const float rq = sqrtf(sq * (1.0f / 1024.0f) + 1e-5f);
    const float graw = sd / (rk * rq) * (1.0f / 32.0f);   // sqrt(C)=32
    const float sgn = (graw >= 0.f) ? 1.f : -1.f;
    const float gate = 1.f / (1.f + expf(-sgn * sqrtf(fmaxf(fabsf(graw), 1e-6f))));
    const float rv = sqrtf(gate * gate * mv + 1e-5f);
    gate_o[bt * Gg + g]  = gate;
    snorm_o[bt * Gg + g] = gate / rv;
  }
}

// ---------------------------------------------------------------------------
// Conv: lags {0,3,6,9} share t mod 3 -> 3 phase subsequences, lag-1 K=4 conv.
// Thread = (b,g,c,phase,chunk); 3 running normed values; 3-step halo.
// ---------------------------------------------------------------------------
static constexpr int CJ  = 128;
static constexpr int NCH = 11;   // ceil(ceil(4096/3)/128)

__global__ __launch_bounds__(256)
void conv_kernel(const float* __restrict__ vproj, const float* __restrict__ gate,
                 const float* __restrict__ snorm, const float* __restrict__ wnm,
                 const float* __restrict__ cw, float* __restrict__ out)
{
  int x = blockIdx.x;
  const int cb = x & 3;  x >>= 2;
  const int p  = x % 3;  x /= 3;
  const int ch = x % NCH; x /= NCH;
  const int g  = x & 3;  x >>= 2;
  const int b  = x;
  const int c  = cb * 256 + threadIdx.x;

  const float wn = wnm[g * Cc + c];
  const float4 w = ((const float4*)cw)[g * Cc + c];

  int t = p + 3 * (ch * CJ);
  if (t >= Tt) return;

  float n1 = 0.f, n2 = 0.f, n3 = 0.f;
#pragma unroll
  for (int h = 3; h >= 1; --h) {
    const int th = t - 3 * h;
    float nv = 0.f;
    if (th >= 0) {
      const int bt = b * Tt + th;
      nv = vproj[(size_t)bt * Cc + c] * snorm[bt * Gg + g] * wn;
    }
    n3 = n2; n2 = n1; n1 = nv;
  }

  for (int j = 0; j < CJ && t < Tt; ++j, t += 3) {
    const int bt = b * Tt + t;
    const float vp  = vproj[(size_t)bt * Cc + c];
    const float gt  = gate[bt * Gg + g];
    const float sn  = snorm[bt * Gg + g];
    const float cur = vp * sn * wn;
    const float a   = w.x * n3 + w.y * n2 + w.z * n1 + w.w * cur;
    const float si  = a / (1.f + __expf(-a));
    out[((size_t)bt * Gg + g) * Cc + c] = vp * gt + si;
    n3 = n2; n2 = n1; n1 = cur;
  }
}

// ---------------------------------------------------------------------------
extern "C" void kernel_launch(void* const* d_in, const int* in_sizes, int n_in,
                              void* d_out, int out_size, void* d_ws, size_t ws_size,
                              hipStream_t stream)
{
  const float* emb   = (const float*)d_in[0];
  const float* hid   = (const float*)d_in[1];
  const float* key_w = (const float*)d_in[2];
  const float* key_b = (const float*)d_in[3];
  const float* val_w = (const float*)d_in[4];
  const float* val_b = (const float*)d_in[5];
  const float* wkn   = (const float*)d_in[6];
  const float* wqn   = (const float*)d_in[7];
  const float* wnm   = (const float*)d_in[8];
  const float* cwt   = (const float*)d_in[9];
  float* out = (float*)d_out;

  // ws: embH 16.8M | embL 16.8M | kwH 8.4M | kwL 8.4M | vwB 2.1M |
  //     vproj 33.5M | k2/dot/q2/gate/snorm 5x128K   (~86.6 MB)
  char* ws = (char*)d_ws;
  ushort* embH  = (ushort*)ws;  ws += (size_t)Mm * Cc * 2;
  ushort* embL  = (ushort*)ws;  ws += (size_t)Mm * Cc * 2;
  ushort* kwH   = (ushort*)ws;  ws += (size_t)GC * Cc * 2;
  ushort* kwL   = (ushort*)ws;  ws += (size_t)GC * Cc * 2;
  ushort* vwB   = (ushort*)ws;  ws += (size_t)Cc * Cc * 2;
  float*  vproj = (float*)ws;   ws += (size_t)Mm * Cc * 4;
  float*  k2p   = (float*)ws;   ws += (size_t)Mm * Gg * 4;
  float*  dotp  = (float*)ws;   ws += (size_t)Mm * Gg * 4;
  float*  q2p   = (float*)ws;   ws += (size_t)Mm * Gg * 4;
  float*  gate  = (float*)ws;   ws += (size_t)Mm * Gg * 4;
  float*  snorm = (float*)ws;

  // zero the atomic partials (contiguous k2p|dotp|q2p)
  hipMemsetAsync(k2p, 0, (size_t)3 * Mm * Gg * 4, stream);

  dim3 blk(256);
  cvt_split<<<dim3((Mm * Cc / 4) / 256), blk, 0, stream>>>(emb,   embH, embL, Mm * Cc / 4);
  cvt_split<<<dim3((GC * Cc / 4) / 256), blk, 0, stream>>>(key_w, kwH,  kwL,  GC * Cc / 4);
  cvt_bf16 <<<dim3((Cc * Cc / 4) / 256), blk, 0, stream>>>(val_w, vwB,  Cc * Cc / 4);

  gemm_key_fused<<<dim3(GC / 128, Mm / 128), blk, 0, stream>>>(
      embH, embL, kwH, kwL, key_b, hid, wkn, wqn, k2p, dotp, q2p);

  gemm_bt<float><<<dim3(Cc / 128, Mm / 128), blk, 0, stream>>>(
      embH, vwB, val_b, vproj, Mm, Cc, Cc);

  finalize_kernel<<<dim3(Mm), blk, 0, stream>>>(vproj, k2p, dotp, q2p, gate, snorm);

  const int nblocks = Bb * Gg * NCH * 3 * (Cc / 256);  // 1056
  conv_kernel<<<dim3(nblocks), blk, 0, stream>>>(vproj, gate, snorm, wnm, cwt, out);
}

// Round 3
// 600.629 us; speedup vs baseline: 1.1418x; 1.0608x over previous
//
#include <hip/hip_runtime.h>
#include <hip/hip_bf16.h>
#include <cstdint>
#include <cstddef>

using bf16 = __hip_bfloat16;

typedef __bf16 bf16x8_t __attribute__((ext_vector_type(8)));
typedef float  f32x4_t  __attribute__((ext_vector_type(4)));

static constexpr int Bb = 2;
static constexpr int Tt = 4096;
static constexpr int Gg = 4;
static constexpr int Cc = 1024;
static constexpr int Mm = Bb * Tt;   // 8192 rows (b*T+t)
static constexpr int GC = Gg * Cc;   // 4096

__device__ __forceinline__ float bfbits2f(unsigned u) {
  union { unsigned i; float f; } c; c.i = u << 16; return c.f;
}
__device__ __forceinline__ ushort f2bfbits(float v) {
  union { __hip_bfloat16 h; ushort u; } c; c.h = __float2bfloat16(v); return c.u;
}

__device__ __forceinline__ void store_val(bf16* p, float v)  { *p = __float2bfloat16(v); }
__device__ __forceinline__ void store_val(float* p, float v) { *p = v; }

// global -> LDS direct DMA, 16 B per lane. LDS dest must be the wave-uniform
// base (HW computes base + lane*16); global address is per-lane.
__device__ __forceinline__ void gld_lds16(const ushort* g, ushort* l) {
  __builtin_amdgcn_global_load_lds(
      (const __attribute__((address_space(1))) void*)g,
      (__attribute__((address_space(3))) void*)l, 16, 0, 0);
}

// ---------------------------------------------------------------------------
// fp32 -> bf16 (plain) and fp32 -> (hi, lo) split: hi = bf16(x),
// lo = bf16(x - hi). x-hi is exact in fp32 (Sterbenz), so hi+lo carries
// ~16 mantissa bits; bf16's fp32 exponent range means no subnormal hazards.
// ---------------------------------------------------------------------------
__global__ __launch_bounds__(256)
void cvt_bf16(const float* __restrict__ in, ushort* __restrict__ out, int n4)
{
  const int i = blockIdx.x * 256 + threadIdx.x;
  if (i >= n4) return;
  const float4 v = ((const float4*)in)[i];
  ushort4 o;
  o.x = f2bfbits(v.x); o.y = f2bfbits(v.y);
  o.z = f2bfbits(v.z); o.w = f2bfbits(v.w);
  ((ushort4*)out)[i] = o;
}

__global__ __launch_bounds__(256)
void cvt_split(const float* __restrict__ in, ushort* __restrict__ hi,
               ushort* __restrict__ lo, int n4)
{
  const int i = blockIdx.x * 256 + threadIdx.x;
  if (i >= n4) return;
  const float4 v = ((const float4*)in)[i];
  ushort4 h, l;
  h.x = f2bfbits(v.x); l.x = f2bfbits(v.x - bfbits2f(h.x));
  h.y = f2bfbits(v.y); l.y = f2bfbits(v.y - bfbits2f(h.y));
  h.z = f2bfbits(v.z); l.z = f2bfbits(v.z - bfbits2f(h.z));
  h.w = f2bfbits(v.w); l.w = f2bfbits(v.w - bfbits2f(h.w));
  ((ushort4*)hi)[i] = h;
  ((ushort4*)lo)[i] = l;
}

// ---------------------------------------------------------------------------
// GEMM1 (fused): split-bf16  k = embH@kwH^T + embH@kwL^T + embL@kwH^T + key_b,
// fp32 acc. R3 change: the 3 split passes are FUSED into one K-loop. Per
// 64-wide K-step we stage 4 tiles (embH, embL, kwH, kwL = 64 KiB LDS) and
// issue 96 MFMAs (H@H + H@L + L@H) per barrier-pair instead of 32 — the R2
// counters showed conflicts=0 / HBM=14% / MfmaUtil=26%, i.e. the 2-phase
// vmcnt(0)+barrier drain was ~2/3 of cycles; tripling MFMA-per-barrier
// amortizes it. Same products, per-kt-interleaved fp32 summation order.
// Epilogue (gate partials + atomicAdd) unchanged.
// T2 st-8x64 XOR swizzle kept (rule #21: linear LDS dest + pre-swizzled
// global source + same XOR on ds_read).
// A-frag A[m=lane&15][k=(lane>>4)*8+j]; C/D col=lane&15,row=(lane>>4)*4+reg.
// ---------------------------------------------------------------------------
__global__ __launch_bounds__(256, 2)
void gemm_key_fused(const ushort* __restrict__ embH, const ushort* __restrict__ embL,
                    const ushort* __restrict__ kwH,  const ushort* __restrict__ kwL,
                    const float* __restrict__ key_b, const float* __restrict__ hid,
                    const float* __restrict__ wkn,   const float* __restrict__ wqn,
                    float* __restrict__ k2_part, float* __restrict__ dot_part,
                    float* __restrict__ q2_part)
{
  constexpr int K = Cc;  // 1024
  __shared__ __align__(16) ushort sAH[128 * 64];
  __shared__ __align__(16) ushort sAL[128 * 64];
  __shared__ __align__(16) ushort sBH[128 * 64];
  __shared__ __align__(16) ushort sBL[128 * 64];

  const int tid  = threadIdx.x;
  const int lane = tid & 63;
  const int wave = tid >> 6;
  const int wm   = wave & 1;
  const int wn   = wave >> 1;
  const int row0 = blockIdx.y * 128;
  const int col0 = blockIdx.x * 128;

  // staging geometry: round p covers rows [p*32, p*32+32); thread t covers
  // row p*32 + (t>>3). LDS dest is linear (lane*16 B off the wave base);
  // the SOURCE column is pre-swizzled so LDS holds the st-8x64 layout.
  const int srow = tid >> 3;                                  // 0..31
  const int scol = ((tid & 7) ^ (srow & 7)) * 8;              // swizzled col
  const int wofs = wave * 512;                                // + p*2048/round

  f32x4_t acc[4][4] = {};

  for (int kt = 0; kt < K; kt += 64) {
#pragma unroll
    for (int p = 0; p < 4; ++p) {
      const size_t aoff = (size_t)(row0 + p * 32 + srow) * K + kt + scol;
      const size_t boff = (size_t)(col0 + p * 32 + srow) * K + kt + scol;
      gld_lds16(embH + aoff, sAH + p * 2048 + wofs);
      gld_lds16(embL + aoff, sAL + p * 2048 + wofs);
      gld_lds16(kwH  + boff, sBH + p * 2048 + wofs);
      gld_lds16(kwL  + boff, sBL + p * 2048 + wofs);
    }
    __syncthreads();

#pragma unroll
    for (int ks = 0; ks < 2; ++ks) {
      const int cb = ks * 4 + (lane >> 4);
      const int ce = ((cb ^ (lane & 7)) * 8);   // swizzled read col (elems)
      bf16x8_t afH[4], afL[4], bfH[4], bfL[4];
#pragma unroll
      for (int mi = 0; mi < 4; ++mi) {
        const int r = wm * 64 + mi * 16 + (lane & 15);
        afH[mi] = *(const bf16x8_t*)(sAH + r * 64 + ce);
        afL[mi] = *(const bf16x8_t*)(sAL + r * 64 + ce);
      }
#pragma unroll
      for (int ni = 0; ni < 4; ++ni) {
        const int r = wn * 64 + ni * 16 + (lane & 15);
        bfH[ni] = *(const bf16x8_t*)(sBH + r * 64 + ce);
        bfL[ni] = *(const bf16x8_t*)(sBL + r * 64 + ce);
      }
#pragma unroll
      for (int mi = 0; mi < 4; ++mi)
#pragma unroll
        for (int ni = 0; ni < 4; ++ni) {
          acc[mi][ni] = __builtin_amdgcn_mfma_f32_16x16x32_bf16(
              afH[mi], bfH[ni], acc[mi][ni], 0, 0, 0);
          acc[mi][ni] = __builtin_amdgcn_mfma_f32_16x16x32_bf16(
              afH[mi], bfL[ni], acc[mi][ni], 0, 0, 0);
          acc[mi][ni] = __builtin_amdgcn_mfma_f32_16x16x32_bf16(
              afL[mi], bfH[ni], acc[mi][ni], 0, 0, 0);
        }
    }
    __syncthreads();
  }

  // ---- fused gate-reduction epilogue ----
  const int lrow = lane >> 4;
  const int lcol = lane & 15;
  const int g    = col0 >> 10;   // 128-col block lies within one group

  float s2[4][4] = {};  // [mi][reg] sum_ni k^2
  float su[4][4] = {};  // [mi][reg] sum_ni k*wk*q*wq
  float sq[4][4] = {};  // [mi][reg] sum_ni q^2

#pragma unroll
  for (int ni = 0; ni < 4; ++ni) {
    const int col = col0 + wn * 64 + ni * 16 + lcol;
    const float kb = key_b[col];
    const float ww = wkn[col] * wqn[col];
#pragma unroll
    for (int mi = 0; mi < 4; ++mi) {
      const int rowb = row0 + wm * 64 + mi * 16 + lrow * 4;
#pragma unroll
      for (int r = 0; r < 4; ++r) {
        const float q = hid[(size_t)(rowb + r) * GC + col];
        const float k = acc[mi][ni][r] + kb;
        s2[mi][r] += k * k;
        su[mi][r] += k * ww * q;
        sq[mi][r] += q * q;
      }
    }
  }
  // reduce across the 16 lanes (lane&15) holding the same rows
#pragma unroll
  for (int off = 1; off < 16; off <<= 1) {
#pragma unroll
    for (int mi = 0; mi < 4; ++mi)
#pragma unroll
      for (int r = 0; r < 4; ++r) {
        s2[mi][r] += __shfl_xor(s2[mi][r], off);
        su[mi][r] += __shfl_xor(su[mi][r], off);
        sq[mi][r] += __shfl_xor(sq[mi][r], off);
      }
  }
  if (lcol == 0) {
#pragma unroll
    for (int mi = 0; mi < 4; ++mi) {
      const int rowb = row0 + wm * 64 + mi * 16 + lrow * 4;
#pragma unroll
      for (int r = 0; r < 4; ++r) {
        atomicAdd(&k2_part[(rowb + r) * Gg + g],  s2[mi][r]);
        atomicAdd(&dot_part[(rowb + r) * Gg + g], su[mi][r]);
        atomicAdd(&q2_part[(rowb + r) * Gg + g],  sq[mi][r]);
      }
    }
  }
}

// ---------------------------------------------------------------------------
// GEMM2: vproj = embH @ vwB^T + val_b  (plain bf16, fp32 out).
// R2 structure: global_load_lds + T2 swizzle.
// ---------------------------------------------------------------------------
template <typename OutT>
__global__ __launch_bounds__(256, 2)
void gemm_bt(const ushort* __restrict__ A, const ushort* __restrict__ Bm,
             const float* __restrict__ bias, OutT* __restrict__ C,
             int M, int N, int K)
{
  __shared__ __align__(16) ushort sA[128 * 64];
  __shared__ __align__(16) ushort sB[128 * 64];

  const int tid  = threadIdx.x;
  const int lane = tid & 63;
  const int wave = tid >> 6;
  const int wm   = wave & 1;
  const int wn   = wave >> 1;
  const int row0 = blockIdx.y * 128;
  const int col0 = blockIdx.x * 128;

  const int srow = tid >> 3;
  const int scol = ((tid & 7) ^ (srow & 7)) * 8;
  ushort* aWB = sA + wave * 512;
  ushort* bWB = sB + wave * 512;

  f32x4_t acc[4][4] = {};

  for (int kt = 0; kt < K; kt += 64) {
#pragma unroll
    for (int p = 0; p < 4; ++p) {
      gld_lds16(A  + (size_t)(row0 + p * 32 + srow) * K + kt + scol,
                aWB + p * 2048);
      gld_lds16(Bm + (size_t)(col0 + p * 32 + srow) * K + kt + scol,
                bWB + p * 2048);
    }
    __syncthreads();

#pragma unroll
    for (int ks = 0; ks < 2; ++ks) {
      const int cb = ks * 4 + (lane >> 4);
      const int ce = ((cb ^ (lane & 7)) * 8);
      bf16x8_t af[4], bfr[4];
#pragma unroll
      for (int mi = 0; mi < 4; ++mi) {
        const int r = wm * 64 + mi * 16 + (lane & 15);
        af[mi] = *(const bf16x8_t*)(sA + r * 64 + ce);
      }
#pragma unroll
      for (int ni = 0; ni < 4; ++ni) {
        const int r = wn * 64 + ni * 16 + (lane & 15);
        bfr[ni] = *(const bf16x8_t*)(sB + r * 64 + ce);
      }
#pragma unroll
      for (int mi = 0; mi < 4; ++mi)
#pragma unroll
        for (int ni = 0; ni < 4; ++ni)
          acc[mi][ni] = __builtin_amdgcn_mfma_f32_16x16x32_bf16(
              af[mi], bfr[ni], acc[mi][ni], 0, 0, 0);
    }
    __syncthreads();
  }

  const int lrow = lane >> 4;
  const int lcol = lane & 15;
#pragma unroll
  for (int ni = 0; ni < 4; ++ni) {
    const int col = col0 + wn * 64 + ni * 16 + lcol;
    const float bv = bias[col];
#pragma unroll
    for (int mi = 0; mi < 4; ++mi) {
      const int rowb = row0 + wm * 64 + mi * 16 + lrow * 4;
#pragma unroll
      for (int r = 0; r < 4; ++r)
        store_val(&C[(size_t)(rowb + r) * N + col], acc[mi][ni][r] + bv);
    }
  }
}

// ---------------------------------------------------------------------------
// Finalize: per (b,t) compute mean(vproj^2); combine with atomic partials to
// produce gate[b,t,g] and snorm[b,t,g] = gate/rms_v.
// ---------------------------------------------------------------------------
__global__ __launch_bounds__(256)
void finalize_kernel(const float* __restrict__ vproj,
                     const float* __restrict__ k2_part,
                     const float* __restrict__ dot_part,
                     const float* __restrict__ q2_part,
                     float* __restrict__ gate_o, float* __restrict__ snorm_o)
{
  const int bt   = blockIdx.x;
  const int tid  = threadIdx.x;
  const int g    = tid >> 6;
  const int lane = tid & 63;

  const float4 v4 = ((const float4*)(vproj + (size_t)bt * Cc))[tid];
  float pv = v4.x * v4.x + v4.y * v4.y + v4.z * v4.z + v4.w * v4.w;
#pragma unroll
  for (int off = 32; off > 0; off >>= 1) pv += __shfl_xor(pv, off);
  __shared__ float wsum[4];
  if (lane == 0) wsum[g] = pv;
  __syncthreads();

  if (lane == 0) {
    const float mv = (wsum[0] + wsum[1] + wsum[2] + wsum[3]) * (1.0f / 1024.0f);
    const float sk = k2_part[bt * Gg + g];
    const float sd = dot_part[bt * Gg + g];
    const float sq = q2_part[bt * Gg + g];
    const float rk = sqrtf(sk * (1.0f / 1024.0f) + 1e-5f);
    const float rq = sqrtf(sq * (1.0f / 1024.0f) + 1e-5f);
    const float graw = sd / (rk * rq) * (1.0f / 32.0f);   // sqrt(C)=32
    const float sgn = (graw >= 0.f) ? 1.f : -1.f;
    const float gate = 1.f / (1.f + expf(-sgn * sqrtf(fmaxf(fabsf(graw), 1e-6f))));
    const float rv = sqrtf(gate * gate * mv + 1e-5f);
    gate_o[bt * Gg + g]  = gate;
    snorm_o[bt * Gg + g] = gate / rv;
  }
}

// ---------------------------------------------------------------------------
// Conv: lags {0,3,6,9} share t mod 3 -> 3 phase subsequences, lag-1 K=4 conv.
// Thread = (b,g,c,phase,chunk); 3 running normed values; 3-step halo.
// ---------------------------------------------------------------------------
static constexpr int CJ  = 128;
static constexpr int NCH = 11;   // ceil(ceil(4096/3)/128)

__global__ __launch_bounds__(256)
void conv_kernel(const float* __restrict__ vproj, const float* __restrict__ gate,
                 const float* __restrict__ snorm, const float* __restrict__ wnm,
                 const float* __restrict__ cw, float* __restrict__ out)
{
  int x = blockIdx.x;
  const int cb = x & 3;  x >>= 2;
  const int p  = x % 3;  x /= 3;
  const int ch = x % NCH; x /= NCH;
  const int g  = x & 3;  x >>= 2;
  const int b  = x;
  const int c  = cb * 256 + threadIdx.x;

  const float wn = wnm[g * Cc + c];
  const float4 w = ((const float4*)cw)[g * Cc + c];

  int t = p + 3 * (ch * CJ);
  if (t >= Tt) return;

  float n1 = 0.f, n2 = 0.f, n3 = 0.f;
#pragma unroll
  for (int h = 3; h >= 1; --h) {
    const int th = t - 3 * h;
    float nv = 0.f;
    if (th >= 0) {
      const int bt = b * Tt + th;
      nv = vproj[(size_t)bt * Cc + c] * snorm[bt * Gg + g] * wn;
    }
    n3 = n2; n2 = n1; n1 = nv;
  }

  for (int j = 0; j < CJ && t < Tt; ++j, t += 3) {
    const int bt = b * Tt + t;
    const float vp  = vproj[(size_t)bt * Cc + c];
    const float gt  = gate[bt * Gg + g];
    const float sn  = snorm[bt * Gg + g];
    const float cur = vp * sn * wn;
    const float a   = w.x * n3 + w.y * n2 + w.z * n1 + w.w * cur;
    const float si  = a / (1.f + __expf(-a));
    out[((size_t)bt * Gg + g) * Cc + c] = vp * gt + si;
    n3 = n2; n2 = n1; n1 = cur;
  }
}

// ---------------------------------------------------------------------------
extern "C" void kernel_launch(void* const* d_in, const int* in_sizes, int n_in,
                              void* d_out, int out_size, void* d_ws, size_t ws_size,
                              hipStream_t stream)
{
  const float* emb   = (const float*)d_in[0];
  const float* hid   = (const float*)d_in[1];
  const float* key_w = (const float*)d_in[2];
  const float* key_b = (const float*)d_in[3];
  const float* val_w = (const float*)d_in[4];
  const float* val_b = (const float*)d_in[5];
  const float* wkn   = (const float*)d_in[6];
  const float* wqn   = (const float*)d_in[7];
  const float* wnm   = (const float*)d_in[8];
  const float* cwt   = (const float*)d_in[9];
  float* out = (float*)d_out;

  // ws: embH 16.8M | embL 16.8M | kwH 8.4M | kwL 8.4M | vwB 2.1M |
  //     vproj 33.5M | k2/dot/q2/gate/snorm 5x128K   (~86.6 MB)
  char* ws = (char*)d_ws;
  ushort* embH  = (ushort*)ws;  ws += (size_t)Mm * Cc * 2;
  ushort* embL  = (ushort*)ws;  ws += (size_t)Mm * Cc * 2;
  ushort* kwH   = (ushort*)ws;  ws += (size_t)GC * Cc * 2;
  ushort* kwL   = (ushort*)ws;  ws += (size_t)GC * Cc * 2;
  ushort* vwB   = (ushort*)ws;  ws += (size_t)Cc * Cc * 2;
  float*  vproj = (float*)ws;   ws += (size_t)Mm * Cc * 4;
  float*  k2p   = (float*)ws;   ws += (size_t)Mm * Gg * 4;
  float*  dotp  = (float*)ws;   ws += (size_t)Mm * Gg * 4;
  float*  q2p   = (float*)ws;   ws += (size_t)Mm * Gg * 4;
  float*  gate  = (float*)ws;   ws += (size_t)Mm * Gg * 4;
  float*  snorm = (float*)ws;

  // zero the atomic partials (contiguous k2p|dotp|q2p)
  hipMemsetAsync(k2p, 0, (size_t)3 * Mm * Gg * 4, stream);

  dim3 blk(256);
  cvt_split<<<dim3((Mm * Cc / 4) / 256), blk, 0, stream>>>(emb,   embH, embL, Mm * Cc / 4);
  cvt_split<<<dim3((GC * Cc / 4) / 256), blk, 0, stream>>>(key_w, kwH,  kwL,  GC * Cc / 4);
  cvt_bf16 <<<dim3((Cc * Cc / 4) / 256), blk, 0, stream>>>(val_w, vwB,  Cc * Cc / 4);

  gemm_key_fused<<<dim3(GC / 128, Mm / 128), blk, 0, stream>>>(
      embH, embL, kwH, kwL, key_b, hid, wkn, wqn, k2p, dotp, q2p);

  gemm_bt<float><<<dim3(Cc / 128, Mm / 128), blk, 0, stream>>>(
      embH, vwB, val_b, vproj, Mm, Cc, Cc);

  finalize_kernel<<<dim3(Mm), blk, 0, stream>>>(vproj, k2p, dotp, q2p, gate, snorm);

  const int nblocks = Bb * Gg * NCH * 3 * (Cc / 256);  // 1056
  conv_kernel<<<dim3(nblocks), blk, 0, stream>>>(vproj, gate, snorm, wnm, cwt, out);
}